// Round 16
// baseline (416.550 us; speedup 1.0000x reference)
//
#include <hip/hip_runtime.h>

typedef __attribute__((ext_vector_type(8))) short bf16x8;
typedef __attribute__((ext_vector_type(4))) float f32x4;
typedef __attribute__((ext_vector_type(16))) float f32x16;
typedef __attribute__((ext_vector_type(4))) unsigned int u32x4;
typedef __attribute__((ext_vector_type(4))) int s32x4;
typedef unsigned short u16;
typedef unsigned int u32;

#define DI __device__ __forceinline__

constexpr int B_ = 32, CI = 256, LX = 5000, CO = 128, LO = 2500, KW = 9, LP = 2560;

DI float b2f(u16 u) { u32 x = ((u32)u) << 16; return __builtin_bit_cast(float, x); }
DI u16 f2b(float f) {
  u32 x = __builtin_bit_cast(u32, f);
  u32 r = (x + 0x7fffu + ((x >> 16) & 1u)) >> 16;  // RNE
  return (u16)r;
}
DI float elu(float v) { return v > 0.f ? v : expm1f(v); }

// ---------------- K0 (merged prep): blocks 0..127 -> conv weights; 128..131 -> projection mats
__global__ __launch_bounds__(256) void k_prep(const float* __restrict__ w, const float* __restrict__ wq,
                                              const float* __restrict__ wk, const float* __restrict__ wv,
                                              const float* __restrict__ wo, u16* __restrict__ wfmt,
                                              float* __restrict__ alphaf, u16* __restrict__ wThi,
                                              u16* __restrict__ wTlo, u16* __restrict__ wT3) {
  if (blockIdx.x < 128) {
    int o = blockIdx.x;
    const float* wrow = w + o * CI * KW;  // w[o][i][k]
    float s = 0.f;
    for (int idx = threadIdx.x; idx < CI * KW; idx += 256) s += fabsf(wrow[idx]);
    __shared__ float red[256];
    red[threadIdx.x] = s;
    __syncthreads();
    for (int st = 128; st > 0; st >>= 1) {
      if (threadIdx.x < st) red[threadIdx.x] += red[threadIdx.x + st];
      __syncthreads();
    }
    if (threadIdx.x == 0) alphaf[o] = red[0] / (float)(CI * KW);
    for (int idx = threadIdx.x; idx < CI * KW; idx += 256) {
      int i = idx / KW, k = idx - i * KW;
      float v = wrow[idx];
      float sg = v > 0.f ? 1.f : (v < 0.f ? -1.f : 0.f);
      wfmt[(((k * 16) + (i >> 4)) * 128 + o) * 16 + (i & 15)] = f2b(sg);
    }
  } else {
    const float* src[4] = {wq, wk, wv, wo};
    int mat = blockIdx.x - 128;
    const float* m = src[mat];
    u16* dh = wThi + mat * CO * CO;
    u16* dl = wTlo + mat * CO * CO;
    for (int idx = threadIdx.x; idx < CO * CO; idx += 256) {
      int nn = idx >> 7, kkn = idx & 127;  // n_out, k_in
      float v = m[kkn * CO + nn];
      u16 hi = f2b(v);
      u16 lo = f2b(v - b2f(hi));
      dh[idx] = hi;
      dl[idx] = lo;
      if (mat < 3) {
        int nt = nn >> 4, n = nn & 15, ks = kkn >> 5, gj = kkn & 31;
        size_t base = (size_t)((mat * 4 + ks) * 8 + nt) * 1024 + n * 32 + gj;
        wT3[base] = hi;
        wT3[base + 512] = lo;
      }
    }
  }
}

// ---------------- K1: conv implicit-GEMM (r13 geometry) with upgraded bank swizzle:
// s' = ((p>>1) ^ ((p>>1)>>3)) & 15 folds bit3 into bank bits -> cols {c,c+8,c+16,c+24}
// no longer collide (read side), and staging writes spread across banks too.
__global__ __launch_bounds__(256) void k_conv(const float* __restrict__ x, const u16* __restrict__ wfmt,
                                              const float* __restrict__ bias, const float* __restrict__ alphaf,
                                              float* __restrict__ y1) {
  const int ltile = blockIdx.x, b = blockIdx.y;
  const int l0 = ltile * 32;
  const int lin0 = 2 * l0 - 4;  // multiple of 4
  alignas(16) __shared__ u16 xsh[72 * 136];  // hi plane [p][swizzled ch]
  alignas(16) __shared__ u16 xsl[72 * 136];  // lo plane
  const int tid = threadIdx.x;
  const int wave = tid >> 6, lane = tid & 63;
  const int col = lane & 31, g = lane >> 5;
  const int o0 = wave * 32;  // wave's 32 output channels
  f32x16 acch = {};
  f32x16 accl = {};
  for (int cpass = 0; cpass < 2; ++cpass) {
    const int c0 = cpass * 128;
    if (cpass) __syncthreads();  // pass-0 reads complete before overwrite
#pragma unroll
    for (int it = 0; it < 9; ++it) {  // 2304 float4 = 128 ch x 18
      int idx = tid + it * 256;
      int i = idx / 18, q = idx - i * 18;
      int lin = lin0 + q * 4;
      const float* xr = x + ((size_t)(b * CI + c0 + i)) * LX;
      float4 v4 = float4{0.f, 0.f, 0.f, 0.f};
      if (lin >= 0 && lin + 4 <= LX) v4 = *reinterpret_cast<const float4*>(xr + lin);
      const float* vp = reinterpret_cast<const float*>(&v4);
#pragma unroll
      for (int e = 0; e < 4; ++e) {
        int p = q * 4 + e;
        float v = vp[e];
        u16 hi = f2b(v);
        int ph = p >> 1;
        int sw = (ph ^ (ph >> 3)) & 15;  // upgraded XOR swizzle
        int colx = (((i >> 3) ^ sw) << 3) | (i & 7);
        xsh[p * 136 + colx] = hi;
        xsl[p * 136 + colx] = f2b(v - b2f(hi));
      }
    }
    __syncthreads();
    for (int kk = 0; kk < KW; ++kk) {
      bf16x8 af[8];
#pragma unroll
      for (int icg = 0; icg < 8; ++icg) {  // coalesced weight fragments (L2-resident)
        int chunk = kk * 16 + cpass * 8 + icg;
        af[icg] = *reinterpret_cast<const bf16x8*>(wfmt + ((size_t)chunk * 128 + o0 + col) * 16 + g * 8);
      }
      const int p = 2 * col + kk;
      const int prow = p * 136;
      const int ph = p >> 1;
      const int s = (ph ^ (ph >> 3)) & 15;  // must match staging swizzle
#pragma unroll
      for (int icg = 0; icg < 8; ++icg) {
        int blkoff = (((icg * 2 + g) ^ s) << 3);
        bf16x8 bh = *reinterpret_cast<const bf16x8*>(&xsh[prow + blkoff]);
        bf16x8 bl = *reinterpret_cast<const bf16x8*>(&xsl[prow + blkoff]);
        acch = __builtin_amdgcn_mfma_f32_32x32x16_bf16(af[icg], bh, acch, 0, 0, 0);
        accl = __builtin_amdgcn_mfma_f32_32x32x16_bf16(af[icg], bl, accl, 0, 0, 0);
      }
    }
  }
  const int l = l0 + col;
  if (l < LO) {
#pragma unroll
    for (int r = 0; r < 16; ++r) {
      int o = o0 + (r & 3) + 8 * (r >> 2) + 4 * g;
      y1[(b * CO + o) * LO + l] = alphaf[o] * (acch[r] + accl[r]) + bias[o];
    }
  }
}

// ---------------- K2: BN stats (deterministic two-stage, float4 loads)
__global__ __launch_bounds__(256) void k_stats(const float* __restrict__ y1, float* __restrict__ ps,
                                               float* __restrict__ ps2) {
  int o = blockIdx.x, b = blockIdx.y;
  const float4* row = reinterpret_cast<const float4*>(y1 + (size_t)(b * CO + o) * LO);  // 625 float4
  float s = 0.f, s2 = 0.f;
  for (int i = threadIdx.x; i < 625; i += 256) {
    float4 v = row[i];
    s += v.x + v.y + v.z + v.w;
    s2 += v.x * v.x + v.y * v.y + v.z * v.z + v.w * v.w;
  }
  __shared__ float r1[256], r2[256];
  r1[threadIdx.x] = s;
  r2[threadIdx.x] = s2;
  __syncthreads();
  for (int st = 128; st > 0; st >>= 1) {
    if (threadIdx.x < st) {
      r1[threadIdx.x] += r1[threadIdx.x + st];
      r2[threadIdx.x] += r2[threadIdx.x + st];
    }
    __syncthreads();
  }
  if (threadIdx.x == 0) {
    ps[b * CO + o] = r1[0];
    ps2[b * CO + o] = r2[0];
  }
}

__global__ void k_bnparams(const float* __restrict__ ps, const float* __restrict__ ps2,
                           const float* __restrict__ gamma, const float* __restrict__ beta,
                           float* __restrict__ bnsc, float* __restrict__ bnsh) {
  int o = threadIdx.x;
  float s = 0.f, s2 = 0.f;
  for (int b = 0; b < B_; ++b) {
    s += ps[b * CO + o];
    s2 += ps2[b * CO + o];
  }
  const float inv_n = 1.f / (float)(B_ * LO);
  float mu = s * inv_n;
  float var = s2 * inv_n - mu * mu;
  float sc = gamma[o] * rsqrtf(var + 1e-5f);
  bnsc[o] = sc;
  bnsh[o] = beta[o] - mu * sc;
}

// ---------------- K5: Q,K,V projections; all spikes stored as i8.
__global__ __launch_bounds__(256) void k_qkv(const float* __restrict__ y1, const float* __restrict__ bnsc,
                                             const float* __restrict__ bnsh, const u16* __restrict__ wT3,
                                             signed char* __restrict__ sq8, signed char* __restrict__ sk8,
                                             signed char* __restrict__ sv8) {
  int tile = blockIdx.x, b = blockIdx.y;
  int tid = threadIdx.x, wave = tid >> 6, lane = tid & 63, n = lane & 15, g = lane >> 4;
  const int t0 = tile * 64;
  alignas(16) __shared__ u16 hshi[64 * 136];
  alignas(16) __shared__ u16 hslo[64 * 136];
  {
    int t = tid & 63;
    int l = t0 + t;
    if (l > LO - 1) l = LO - 1;
    for (int c = (tid >> 6); c < CO; c += 4) {
      float raw = y1[((size_t)b * CO + c) * LO + l];
      float e = elu(raw * bnsc[c] + bnsh[c]);
      u16 hi = f2b(e);
      hshi[t * 136 + c] = hi;
      hslo[t * 136 + c] = f2b(e - b2f(hi));
    }
  }
  __syncthreads();
  const u16* ah = &hshi[(wave * 16 + n) * 136];
  const u16* al = &hslo[(wave * 16 + n) * 136];
  signed char* outs[3] = {sq8, sk8, sv8};
  for (int mat = 0; mat < 3; ++mat) {
    f32x4 acc[8] = {};
#pragma unroll
    for (int ks = 0; ks < 4; ++ks) {
      bf16x8 ahi = *reinterpret_cast<const bf16x8*>(ah + ks * 32 + g * 8);
      bf16x8 alo = *reinterpret_cast<const bf16x8*>(al + ks * 32 + g * 8);
      const u16* wbase = wT3 + (size_t)((mat * 4 + ks) * 8) * 1024 + n * 32 + g * 8;
#pragma unroll
      for (int nt = 0; nt < 8; ++nt) {
        bf16x8 bhi = *reinterpret_cast<const bf16x8*>(wbase + nt * 1024);
        bf16x8 blo = *reinterpret_cast<const bf16x8*>(wbase + nt * 1024 + 512);
        acc[nt] = __builtin_amdgcn_mfma_f32_16x16x32_bf16(ahi, bhi, acc[nt], 0, 0, 0);
        acc[nt] = __builtin_amdgcn_mfma_f32_16x16x32_bf16(ahi, blo, acc[nt], 0, 0, 0);
        acc[nt] = __builtin_amdgcn_mfma_f32_16x16x32_bf16(alo, bhi, acc[nt], 0, 0, 0);
        acc[nt] = __builtin_amdgcn_mfma_f32_16x16x32_bf16(alo, blo, acc[nt], 0, 0, 0);
      }
    }
    signed char* so = outs[mat];
#pragma unroll
    for (int nt = 0; nt < 8; ++nt) {
#pragma unroll
      for (int r = 0; r < 4; ++r) {
        int tok = t0 + wave * 16 + g * 4 + r;
        int c = nt * 16 + n;
        bool valid = tok < LO;
        float v = valid ? acc[nt][r] : 0.f;
        so[((size_t)b * LP + tok) * CO + c] = v > 0.f ? 1 : 0;
      }
    }
  }
}

// ---------------- K6: pool (BN+ELU fused) over global-attn chunks.
__global__ __launch_bounds__(64) void k_poolh(const float* __restrict__ y1, const float* __restrict__ bnsc,
                                              const float* __restrict__ bnsh, float* __restrict__ hsum) {
  int c = blockIdx.x, b = blockIdx.y, lane = threadIdx.x;
  const float* row = y1 + ((size_t)b * CO + c) * LO;
  const float sc = bnsc[c], sh = bnsh[c];
  __shared__ float bins[16][64];
#pragma unroll
  for (int ch = 0; ch < 16; ++ch) bins[ch][lane] = 0.f;
  for (int j = lane; j < LO; j += 64) {
    float e = elu(row[j] * sc + sh);
    bins[j / 157][lane] += e;
  }
#pragma unroll
  for (int ch = 0; ch < 16; ++ch) {
    float v = bins[ch][lane];
    for (int off = 32; off > 0; off >>= 1) v += __shfl_down(v, off);
    if (lane == 0) hsum[(b * 16 + ch) * CO + c] = v;
  }
}

// ---------------- K7: pooled K/V spikes -> kv8[d][c] = sum_g skg[c]*svg[d] (exact integer i8)
__global__ __launch_bounds__(256) void k_kv2(const float* __restrict__ hsum, const float* __restrict__ wk,
                                             const float* __restrict__ wv, signed char* __restrict__ kv8) {
  int b = blockIdx.x;
  __shared__ float hs[16 * 128], sks[16 * 128], svs[16 * 128];
  for (int i = threadIdx.x; i < 2048; i += 256) hs[i] = hsum[b * 2048 + i];
  __syncthreads();
  for (int idx = threadIdx.x; idx < 2048; idx += 256) {
    int gg = idx >> 7, c = idx & 127;
    float ak = 0.f, av = 0.f;
    for (int k = 0; k < 128; ++k) {
      float hv = hs[gg * 128 + k];
      ak += hv * wk[k * CO + c];
      av += hv * wv[k * CO + c];
    }
    sks[idx] = ak > 0.f ? 1.f : 0.f;
    svs[idx] = av > 0.f ? 1.f : 0.f;
  }
  __syncthreads();
  for (int idx = threadIdx.x; idx < CO * CO; idx += 256) {
    int d = idx >> 7, c = idx & 127;
    float s = 0.f;
#pragma unroll
    for (int gg = 0; gg < 16; ++gg) s += sks[gg * 128 + c] * svs[gg * 128 + d];
    kv8[b * CO * CO + idx] = (signed char)s;  // integer <= 16, exact
  }
}

// ---------------- K8: fused attention v5 — sv read as i8, unpacked to bf16 during svT staging;
// i8 QK^T + i8 global; bf16 PV; shfl-P; coalesced transposed phase-E stores.
__global__ __launch_bounds__(512) void k_attn(const signed char* __restrict__ sq8,
                                              const signed char* __restrict__ sk8,
                                              const signed char* __restrict__ sv8,
                                              const signed char* __restrict__ kv8,
                                              const u16* __restrict__ woT, const float* __restrict__ y1,
                                              const float* __restrict__ bnsc, const float* __restrict__ bnsh,
                                              float* __restrict__ out) {
  const int win = blockIdx.x, b = blockIdx.y, qt = blockIdx.z;
  const int T0 = win * 256;
  alignas(16) __shared__ char smem[69632];  // phase A/B: svT[128][264] u16; phase D/E: pw2 + sF
  u16* svT = reinterpret_cast<u16*>(smem);
  const int tid = threadIdx.x, wave = tid >> 6, lane = tid & 63, n = lane & 15, g = lane >> 4;
  for (int i = tid; i < 8192; i += 512) {  // 32768 i8 spikes as u32 quads
    int u = i >> 5, c4 = (i & 31) << 2;
    u32 w4 = *reinterpret_cast<const u32*>(sv8 + ((size_t)b * LP + T0 + u) * CO + c4);
#pragma unroll
    for (int j = 0; j < 4; ++j) {
      svT[(c4 + j) * 264 + u] = ((w4 >> (8 * j)) & 0xffu) ? (u16)0x3F80 : (u16)0;  // bf16 1.0 / 0.0
    }
  }
  __syncthreads();
  {
    const int qbase = wave * 32 + qt * 16;
    // q spikes (i8, 2 fragments cover K=128)
    s32x4 bq8[2];
    const signed char* qrow = sq8 + ((size_t)b * LP + T0 + qbase + n) * CO;
    bq8[0] = *reinterpret_cast<const s32x4*>(qrow + g * 16);
    bq8[1] = *reinterpret_cast<const s32x4*>(qrow + 64 + g * 16);
    // phase A: S^T[u][q] integer-exact via i8 MFMA (lane holds q=n, u = ut*16 + g*4 + r)
    s32x4 pacc[16];
#pragma unroll
    for (int ut = 0; ut < 16; ++ut) pacc[ut] = s32x4{0, 0, 0, 0};
    for (int ut = 0; ut < 16; ++ut) {
      const signed char* krow = sk8 + ((size_t)b * LP + T0 + ut * 16 + n) * CO;
      s32x4 kf0 = *reinterpret_cast<const s32x4*>(krow + g * 16);
      s32x4 kf1 = *reinterpret_cast<const s32x4*>(krow + 64 + g * 16);
      pacc[ut] = __builtin_amdgcn_mfma_i32_16x16x64_i8(kf0, bq8[0], pacc[ut], 0, 0, 0);
      pacc[ut] = __builtin_amdgcn_mfma_i32_16x16x64_i8(kf1, bq8[1], pacc[ut], 0, 0, 0);
    }
    // phase A2: window weights + pack to bf16 pairs (RNE; S integers -> identical P bits)
    const int qblk = (qbase + n) >> 6;
    u32 packed[16][2];
#pragma unroll
    for (int ut = 0; ut < 16; ++ut) {
      u16 pk[4];
#pragma unroll
      for (int r = 0; r < 4; ++r) {
        int uloc = ut * 16 + g * 4 + r;
        float wgt = (1.f / 768.f) + (((uloc >> 6) == qblk) ? (1.f / 192.f) : 0.f);
        pk[r] = f2b((float)pacc[ut][r] * wgt);
      }
      packed[ut][0] = (u32)pk[0] | ((u32)pk[1] << 16);
      packed[ut][1] = (u32)pk[2] | ((u32)pk[3] << 16);
    }
    // phase C (first): global attn, i8 exact -> acco initialized with accg/48
    f32x4 acco[8];
#pragma unroll
    for (int ct = 0; ct < 8; ++ct) {
      s32x4 ag = {0, 0, 0, 0};
      const signed char* kvrow = kv8 + ((size_t)b * CO + ct * 16 + n) * CO;
      s32x4 k0 = *reinterpret_cast<const s32x4*>(kvrow + g * 16);
      s32x4 k1 = *reinterpret_cast<const s32x4*>(kvrow + 64 + g * 16);
      ag = __builtin_amdgcn_mfma_i32_16x16x64_i8(bq8[0], k0, ag, 0, 0, 0);
      ag = __builtin_amdgcn_mfma_i32_16x16x64_i8(bq8[1], k1, ag, 0, 0, 0);
#pragma unroll
      for (int r = 0; r < 4; ++r) acco[ct][r] = (float)ag[r] * (1.f / 48.f);
    }
    // phase B: PV with P delivered by shfl: lane (n,g) needs P[q=n][u=us*32+8g+j]
    const int sl0 = n + 16 * ((g & 1) * 2);
    const int sl1 = sl0 + 16;
    const bool ghi = ((g >> 1) & 1) != 0;
#pragma unroll
    for (int us = 0; us < 8; ++us) {
      u32 a0e = (u32)__shfl((int)packed[us * 2][0], sl0, 64);
      u32 a0o = (u32)__shfl((int)packed[us * 2 + 1][0], sl0, 64);
      u32 a1e = (u32)__shfl((int)packed[us * 2][1], sl0, 64);
      u32 a1o = (u32)__shfl((int)packed[us * 2 + 1][1], sl0, 64);
      u32 a2e = (u32)__shfl((int)packed[us * 2][0], sl1, 64);
      u32 a2o = (u32)__shfl((int)packed[us * 2 + 1][0], sl1, 64);
      u32 a3e = (u32)__shfl((int)packed[us * 2][1], sl1, 64);
      u32 a3o = (u32)__shfl((int)packed[us * 2 + 1][1], sl1, 64);
      u32x4 paw = {ghi ? a0o : a0e, ghi ? a1o : a1e, ghi ? a2o : a2e, ghi ? a3o : a3e};
      bf16x8 pa = __builtin_bit_cast(bf16x8, paw);
#pragma unroll
      for (int ct = 0; ct < 8; ++ct) {
        bf16x8 bv = *reinterpret_cast<const bf16x8*>(&svT[(ct * 16 + n) * 264 + us * 32 + g * 8]);
        acco[ct] = __builtin_amdgcn_mfma_f32_16x16x32_bf16(pa, bv, acco[ct], 0, 0, 0);
      }
    }
    // phase D: attn-out tile -> per-wave bf16 scratch (svT dead after this barrier)
    __syncthreads();
    u16* pw2 = reinterpret_cast<u16*>(smem) + wave * (16 * 136);            // 34816 B total
    float* sF = reinterpret_cast<float*>(smem + 34816) + wave * (64 * 17);  // 34816 B total
#pragma unroll
    for (int ct = 0; ct < 8; ++ct) {
#pragma unroll
      for (int r = 0; r < 4; ++r) {
        pw2[(g * 4 + r) * 136 + ct * 16 + n] = f2b(acco[ct][r]);
      }
    }
    // phase E: wo GEMM; route facc through fp32 LDS tile for coalesced residual+store.
    for (int half = 0; half < 2; ++half) {
#pragma unroll
      for (int ot2 = 0; ot2 < 4; ++ot2) {
        int ot = half * 4 + ot2;
        f32x4 facc = {};
#pragma unroll
        for (int ks = 0; ks < 4; ++ks) {
          bf16x8 af = *reinterpret_cast<const bf16x8*>(&pw2[n * 136 + ks * 32 + g * 8]);
          bf16x8 bw = *reinterpret_cast<const bf16x8*>(&woT[(ot * 16 + n) * CO + ks * 32 + g * 8]);
          facc = __builtin_amdgcn_mfma_f32_16x16x32_bf16(af, bw, facc, 0, 0, 0);
        }
#pragma unroll
        for (int r = 0; r < 4; ++r) sF[(ot2 * 16 + n) * 17 + g * 4 + r] = facc[r];
      }
      // store: lane&15 = l-offset -> 16 consecutive floats per o-row (full 64B lines)
#pragma unroll
      for (int oo = 0; oo < 16; ++oo) {
        int olocal = oo * 4 + (lane >> 4);
        int o = half * 64 + olocal;
        int l = T0 + qbase + (lane & 15);
        float v = sF[olocal * 17 + (lane & 15)];
        if (l < LO) {
          size_t idx = ((size_t)b * CO + o) * LO + l;
          out[idx] = elu(y1[idx] * bnsc[o] + bnsh[o]) + v;
        }
      }
    }
  }
}

extern "C" void kernel_launch(void* const* d_in, const int* in_sizes, int n_in, void* d_out, int out_size,
                              void* d_ws, size_t ws_size, hipStream_t stream) {
  const float* x = (const float*)d_in[0];
  const float* conv_w = (const float*)d_in[1];
  const float* conv_b = (const float*)d_in[2];
  const float* gamma = (const float*)d_in[3];
  const float* beta = (const float*)d_in[4];
  const float* wq = (const float*)d_in[5];
  const float* wk = (const float*)d_in[6];
  const float* wv = (const float*)d_in[7];
  const float* wo = (const float*)d_in[8];
  (void)in_sizes; (void)n_in; (void)out_size; (void)ws_size;

  char* ws = (char*)d_ws;
  size_t off = 0;
  auto alloc = [&](size_t bytes) -> void* {
    void* p = ws + off;
    off += (bytes + 511) & ~(size_t)511;
    return p;
  };
  float* ps = (float*)alloc((size_t)B_ * CO * 4);
  float* ps2 = (float*)alloc((size_t)B_ * CO * 4);
  float* bnsc = (float*)alloc(CO * 4);
  float* bnsh = (float*)alloc(CO * 4);
  float* alphaf = (float*)alloc(CO * 4);
  float* hsum = (float*)alloc((size_t)B_ * 16 * CO * 4);
  signed char* kv8 = (signed char*)alloc((size_t)B_ * CO * CO);
  u16* wfmt = (u16*)alloc((size_t)CO * KW * CI * 2);
  u16* wThi = (u16*)alloc((size_t)4 * CO * CO * 2);
  u16* wTlo = (u16*)alloc((size_t)4 * CO * CO * 2);
  u16* wT3 = (u16*)alloc((size_t)3 * 4 * 8 * 1024 * 2);
  float* y1 = (float*)alloc((size_t)B_ * CO * LO * 4);
  signed char* sqb8 = (signed char*)alloc((size_t)B_ * LP * CO);
  signed char* skb8 = (signed char*)alloc((size_t)B_ * LP * CO);
  signed char* svb8 = (signed char*)alloc((size_t)B_ * LP * CO);

  hipLaunchKernelGGL(k_prep, dim3(132), dim3(256), 0, stream, conv_w, wq, wk, wv, wo, wfmt, alphaf, wThi,
                     wTlo, wT3);
  hipLaunchKernelGGL(k_conv, dim3(80, B_), dim3(256), 0, stream, x, wfmt, conv_b, alphaf, y1);
  hipLaunchKernelGGL(k_stats, dim3(CO, B_), dim3(256), 0, stream, y1, ps, ps2);
  hipLaunchKernelGGL(k_bnparams, dim3(1), dim3(CO), 0, stream, ps, ps2, gamma, beta, bnsc, bnsh);
  hipLaunchKernelGGL(k_qkv, dim3(40, B_), dim3(256), 0, stream, y1, bnsc, bnsh, wT3, sqb8, skb8, svb8);
  hipLaunchKernelGGL(k_poolh, dim3(CO, B_), dim3(64), 0, stream, y1, bnsc, bnsh, hsum);
  hipLaunchKernelGGL(k_kv2, dim3(B_), dim3(256), 0, stream, hsum, wk, wv, kv8);
  hipLaunchKernelGGL(k_attn, dim3(10, B_, 2), dim3(512), 0, stream, sqb8, skb8, svb8, kv8, wThi + 3 * CO * CO,
                     y1, bnsc, bnsh, (float*)d_out);
}

// Round 17
// 401.033 us; speedup vs baseline: 1.0387x; 1.0387x over previous
//
#include <hip/hip_runtime.h>

typedef __attribute__((ext_vector_type(8))) short bf16x8;
typedef __attribute__((ext_vector_type(4))) float f32x4;
typedef __attribute__((ext_vector_type(16))) float f32x16;
typedef __attribute__((ext_vector_type(4))) unsigned int u32x4;
typedef __attribute__((ext_vector_type(4))) int s32x4;
typedef unsigned short u16;
typedef unsigned int u32;

#define DI __device__ __forceinline__

constexpr int B_ = 32, CI = 256, LX = 5000, CO = 128, LO = 2500, KW = 9, LP = 2560;

DI float b2f(u16 u) { u32 x = ((u32)u) << 16; return __builtin_bit_cast(float, x); }
DI u16 f2b(float f) {
  u32 x = __builtin_bit_cast(u32, f);
  u32 r = (x + 0x7fffu + ((x >> 16) & 1u)) >> 16;  // RNE
  return (u16)r;
}
DI float elu(float v) { return v > 0.f ? v : expm1f(v); }

// ---------------- K0 (merged prep): blocks 0..127 -> conv weights; 128..131 -> projection mats
__global__ __launch_bounds__(256) void k_prep(const float* __restrict__ w, const float* __restrict__ wq,
                                              const float* __restrict__ wk, const float* __restrict__ wv,
                                              const float* __restrict__ wo, u16* __restrict__ wfmt,
                                              float* __restrict__ alphaf, u16* __restrict__ wThi,
                                              u16* __restrict__ wTlo, u16* __restrict__ wT3) {
  if (blockIdx.x < 128) {
    int o = blockIdx.x;
    const float* wrow = w + o * CI * KW;  // w[o][i][k]
    float s = 0.f;
    for (int idx = threadIdx.x; idx < CI * KW; idx += 256) s += fabsf(wrow[idx]);
    __shared__ float red[256];
    red[threadIdx.x] = s;
    __syncthreads();
    for (int st = 128; st > 0; st >>= 1) {
      if (threadIdx.x < st) red[threadIdx.x] += red[threadIdx.x + st];
      __syncthreads();
    }
    if (threadIdx.x == 0) alphaf[o] = red[0] / (float)(CI * KW);
    for (int idx = threadIdx.x; idx < CI * KW; idx += 256) {
      int i = idx / KW, k = idx - i * KW;
      float v = wrow[idx];
      float sg = v > 0.f ? 1.f : (v < 0.f ? -1.f : 0.f);
      wfmt[(((k * 16) + (i >> 4)) * 128 + o) * 16 + (i & 15)] = f2b(sg);
    }
  } else {
    const float* src[4] = {wq, wk, wv, wo};
    int mat = blockIdx.x - 128;
    const float* m = src[mat];
    u16* dh = wThi + mat * CO * CO;
    u16* dl = wTlo + mat * CO * CO;
    for (int idx = threadIdx.x; idx < CO * CO; idx += 256) {
      int nn = idx >> 7, kkn = idx & 127;  // n_out, k_in
      float v = m[kkn * CO + nn];
      u16 hi = f2b(v);
      u16 lo = f2b(v - b2f(hi));
      dh[idx] = hi;
      dl[idx] = lo;
      if (mat < 3) {
        int nt = nn >> 4, n = nn & 15, ks = kkn >> 5, gj = kkn & 31;
        size_t base = (size_t)((mat * 4 + ks) * 8 + nt) * 1024 + n * 32 + gj;
        wT3[base] = hi;
        wT3[base + 512] = lo;
      }
    }
  }
}

// ---------------- K1: conv implicit-GEMM (exact r15-proven 177.9us form)
__global__ __launch_bounds__(256) void k_conv(const float* __restrict__ x, const u16* __restrict__ wfmt,
                                              const float* __restrict__ bias, const float* __restrict__ alphaf,
                                              float* __restrict__ y1) {
  const int ltile = blockIdx.x, b = blockIdx.y;
  const int l0 = ltile * 32;
  const int lin0 = 2 * l0 - 4;  // multiple of 4
  alignas(16) __shared__ u16 xsh[72 * 136];  // hi plane [p][swizzled ch]
  alignas(16) __shared__ u16 xsl[72 * 136];  // lo plane
  const int tid = threadIdx.x;
  const int wave = tid >> 6, lane = tid & 63;
  const int col = lane & 31, g = lane >> 5;
  const int o0 = wave * 32;  // wave's 32 output channels
  f32x16 acch = {};
  f32x16 accl = {};
  for (int cpass = 0; cpass < 2; ++cpass) {
    const int c0 = cpass * 128;
    if (cpass) __syncthreads();  // pass-0 reads complete before overwrite
#pragma unroll
    for (int it = 0; it < 9; ++it) {  // 2304 float4 = 128 ch x 18
      int idx = tid + it * 256;
      int i = idx / 18, q = idx - i * 18;
      int lin = lin0 + q * 4;
      const float* xr = x + ((size_t)(b * CI + c0 + i)) * LX;
      float4 v4 = float4{0.f, 0.f, 0.f, 0.f};
      if (lin >= 0 && lin + 4 <= LX) v4 = *reinterpret_cast<const float4*>(xr + lin);
      const float* vp = reinterpret_cast<const float*>(&v4);
#pragma unroll
      for (int e = 0; e < 4; ++e) {
        int p = q * 4 + e;
        float v = vp[e];
        u16 hi = f2b(v);
        int colx = ((((i >> 3) ^ ((p >> 1) & 15)) & 15) << 3) | (i & 7);  // 4-bit XOR swizzle
        xsh[p * 136 + colx] = hi;
        xsl[p * 136 + colx] = f2b(v - b2f(hi));
      }
    }
    __syncthreads();
    for (int kk = 0; kk < KW; ++kk) {
      bf16x8 af[8];
#pragma unroll
      for (int icg = 0; icg < 8; ++icg) {  // coalesced weight fragments (L2-resident)
        int chunk = kk * 16 + cpass * 8 + icg;
        af[icg] = *reinterpret_cast<const bf16x8*>(wfmt + ((size_t)chunk * 128 + o0 + col) * 16 + g * 8);
      }
      const int p = 2 * col + kk;
      const int prow = p * 136;
      const int s = (p >> 1) & 15;
#pragma unroll
      for (int icg = 0; icg < 8; ++icg) {
        int blkoff = (((icg * 2 + g) ^ s) << 3);
        bf16x8 bh = *reinterpret_cast<const bf16x8*>(&xsh[prow + blkoff]);
        bf16x8 bl = *reinterpret_cast<const bf16x8*>(&xsl[prow + blkoff]);
        acch = __builtin_amdgcn_mfma_f32_32x32x16_bf16(af[icg], bh, acch, 0, 0, 0);
        accl = __builtin_amdgcn_mfma_f32_32x32x16_bf16(af[icg], bl, accl, 0, 0, 0);
      }
    }
  }
  const int l = l0 + col;
  if (l < LO) {
#pragma unroll
    for (int r = 0; r < 16; ++r) {
      int o = o0 + (r & 3) + 8 * (r >> 2) + 4 * g;
      y1[(b * CO + o) * LO + l] = alphaf[o] * (acch[r] + accl[r]) + bias[o];
    }
  }
}

// ---------------- K2: BN stats (deterministic two-stage, float4 loads)
__global__ __launch_bounds__(256) void k_stats(const float* __restrict__ y1, float* __restrict__ ps,
                                               float* __restrict__ ps2) {
  int o = blockIdx.x, b = blockIdx.y;
  const float4* row = reinterpret_cast<const float4*>(y1 + (size_t)(b * CO + o) * LO);  // 625 float4
  float s = 0.f, s2 = 0.f;
  for (int i = threadIdx.x; i < 625; i += 256) {
    float4 v = row[i];
    s += v.x + v.y + v.z + v.w;
    s2 += v.x * v.x + v.y * v.y + v.z * v.z + v.w * v.w;
  }
  __shared__ float r1[256], r2[256];
  r1[threadIdx.x] = s;
  r2[threadIdx.x] = s2;
  __syncthreads();
  for (int st = 128; st > 0; st >>= 1) {
    if (threadIdx.x < st) {
      r1[threadIdx.x] += r1[threadIdx.x + st];
      r2[threadIdx.x] += r2[threadIdx.x + st];
    }
    __syncthreads();
  }
  if (threadIdx.x == 0) {
    ps[b * CO + o] = r1[0];
    ps2[b * CO + o] = r2[0];
  }
}

__global__ void k_bnparams(const float* __restrict__ ps, const float* __restrict__ ps2,
                           const float* __restrict__ gamma, const float* __restrict__ beta,
                           float* __restrict__ bnsc, float* __restrict__ bnsh) {
  int o = threadIdx.x;
  float s = 0.f, s2 = 0.f;
  for (int b = 0; b < B_; ++b) {
    s += ps[b * CO + o];
    s2 += ps2[b * CO + o];
  }
  const float inv_n = 1.f / (float)(B_ * LO);
  float mu = s * inv_n;
  float var = s2 * inv_n - mu * mu;
  float sc = gamma[o] * rsqrtf(var + 1e-5f);
  bnsc[o] = sc;
  bnsh[o] = beta[o] - mu * sc;
}

// ---------------- K5: Q,K,V projections v2 — each wave owns 32 tokens (2 A-sets per B-fragment
// load -> wT3 L2 traffic halves). Block = 128 tokens. Per-token math identical to r15.
__global__ __launch_bounds__(256) void k_qkv(const float* __restrict__ y1, const float* __restrict__ bnsc,
                                             const float* __restrict__ bnsh, const u16* __restrict__ wT3,
                                             signed char* __restrict__ sq8, signed char* __restrict__ sk8,
                                             signed char* __restrict__ sv8) {
  int tile = blockIdx.x, b = blockIdx.y;
  int tid = threadIdx.x, wave = tid >> 6, lane = tid & 63, n = lane & 15, g = lane >> 4;
  const int t0 = tile * 128;
  alignas(16) __shared__ u16 hshi[128 * 136];
  alignas(16) __shared__ u16 hslo[128 * 136];
  {
    int t = tid & 127;
    int l = t0 + t;
    if (l > LO - 1) l = LO - 1;
    int cbase = (tid >> 7) * 64;
    for (int cc = 0; cc < 64; ++cc) {
      int c = cbase + cc;
      float raw = y1[((size_t)b * CO + c) * LO + l];
      float e = elu(raw * bnsc[c] + bnsh[c]);
      u16 hi = f2b(e);
      hshi[t * 136 + c] = hi;
      hslo[t * 136 + c] = f2b(e - b2f(hi));
    }
  }
  __syncthreads();
  const u16* ahA = &hshi[(wave * 32 + n) * 136];
  const u16* alA = &hslo[(wave * 32 + n) * 136];
  const u16* ahB = &hshi[(wave * 32 + 16 + n) * 136];
  const u16* alB = &hslo[(wave * 32 + 16 + n) * 136];
  signed char* outs[3] = {sq8, sk8, sv8};
  for (int mat = 0; mat < 3; ++mat) {
    f32x4 accA[8] = {};
    f32x4 accB[8] = {};
#pragma unroll
    for (int ks = 0; ks < 4; ++ks) {
      bf16x8 ahiA = *reinterpret_cast<const bf16x8*>(ahA + ks * 32 + g * 8);
      bf16x8 aloA = *reinterpret_cast<const bf16x8*>(alA + ks * 32 + g * 8);
      bf16x8 ahiB = *reinterpret_cast<const bf16x8*>(ahB + ks * 32 + g * 8);
      bf16x8 aloB = *reinterpret_cast<const bf16x8*>(alB + ks * 32 + g * 8);
      const u16* wbase = wT3 + (size_t)((mat * 4 + ks) * 8) * 1024 + n * 32 + g * 8;
#pragma unroll
      for (int nt = 0; nt < 8; ++nt) {
        bf16x8 bhi = *reinterpret_cast<const bf16x8*>(wbase + nt * 1024);
        bf16x8 blo = *reinterpret_cast<const bf16x8*>(wbase + nt * 1024 + 512);
        accA[nt] = __builtin_amdgcn_mfma_f32_16x16x32_bf16(ahiA, bhi, accA[nt], 0, 0, 0);
        accA[nt] = __builtin_amdgcn_mfma_f32_16x16x32_bf16(ahiA, blo, accA[nt], 0, 0, 0);
        accA[nt] = __builtin_amdgcn_mfma_f32_16x16x32_bf16(aloA, bhi, accA[nt], 0, 0, 0);
        accA[nt] = __builtin_amdgcn_mfma_f32_16x16x32_bf16(aloA, blo, accA[nt], 0, 0, 0);
        accB[nt] = __builtin_amdgcn_mfma_f32_16x16x32_bf16(ahiB, bhi, accB[nt], 0, 0, 0);
        accB[nt] = __builtin_amdgcn_mfma_f32_16x16x32_bf16(ahiB, blo, accB[nt], 0, 0, 0);
        accB[nt] = __builtin_amdgcn_mfma_f32_16x16x32_bf16(aloB, bhi, accB[nt], 0, 0, 0);
        accB[nt] = __builtin_amdgcn_mfma_f32_16x16x32_bf16(aloB, blo, accB[nt], 0, 0, 0);
      }
    }
    signed char* so = outs[mat];
#pragma unroll
    for (int nt = 0; nt < 8; ++nt) {
#pragma unroll
      for (int r = 0; r < 4; ++r) {
        int tokA = t0 + wave * 32 + g * 4 + r;
        int tokB = tokA + 16;
        int c = nt * 16 + n;
        float vA = (tokA < LO) ? accA[nt][r] : 0.f;
        float vB = (tokB < LO) ? accB[nt][r] : 0.f;
        so[((size_t)b * LP + tokA) * CO + c] = vA > 0.f ? 1 : 0;
        so[((size_t)b * LP + tokB) * CO + c] = vB > 0.f ? 1 : 0;
      }
    }
  }
}

// ---------------- K6: pool (BN+ELU fused) over global-attn chunks.
__global__ __launch_bounds__(64) void k_poolh(const float* __restrict__ y1, const float* __restrict__ bnsc,
                                              const float* __restrict__ bnsh, float* __restrict__ hsum) {
  int c = blockIdx.x, b = blockIdx.y, lane = threadIdx.x;
  const float* row = y1 + ((size_t)b * CO + c) * LO;
  const float sc = bnsc[c], sh = bnsh[c];
  __shared__ float bins[16][64];
#pragma unroll
  for (int ch = 0; ch < 16; ++ch) bins[ch][lane] = 0.f;
  for (int j = lane; j < LO; j += 64) {
    float e = elu(row[j] * sc + sh);
    bins[j / 157][lane] += e;
  }
#pragma unroll
  for (int ch = 0; ch < 16; ++ch) {
    float v = bins[ch][lane];
    for (int off = 32; off > 0; off >>= 1) v += __shfl_down(v, off);
    if (lane == 0) hsum[(b * 16 + ch) * CO + c] = v;
  }
}

// ---------------- K7: pooled K/V spikes -> kv8[d][c] = sum_g skg[c]*svg[d] (exact integer i8)
__global__ __launch_bounds__(256) void k_kv2(const float* __restrict__ hsum, const float* __restrict__ wk,
                                             const float* __restrict__ wv, signed char* __restrict__ kv8) {
  int b = blockIdx.x;
  __shared__ float hs[16 * 128], sks[16 * 128], svs[16 * 128];
  for (int i = threadIdx.x; i < 2048; i += 256) hs[i] = hsum[b * 2048 + i];
  __syncthreads();
  for (int idx = threadIdx.x; idx < 2048; idx += 256) {
    int gg = idx >> 7, c = idx & 127;
    float ak = 0.f, av = 0.f;
    for (int k = 0; k < 128; ++k) {
      float hv = hs[gg * 128 + k];
      ak += hv * wk[k * CO + c];
      av += hv * wv[k * CO + c];
    }
    sks[idx] = ak > 0.f ? 1.f : 0.f;
    svs[idx] = av > 0.f ? 1.f : 0.f;
  }
  __syncthreads();
  for (int idx = threadIdx.x; idx < CO * CO; idx += 256) {
    int d = idx >> 7, c = idx & 127;
    float s = 0.f;
#pragma unroll
    for (int gg = 0; gg < 16; ++gg) s += sks[gg * 128 + c] * svs[gg * 128 + d];
    kv8[b * CO * CO + idx] = (signed char)s;  // integer <= 16, exact
  }
}

// ---------------- K8: fused attention v5 (unchanged from r15)
__global__ __launch_bounds__(512) void k_attn(const signed char* __restrict__ sq8,
                                              const signed char* __restrict__ sk8,
                                              const signed char* __restrict__ sv8,
                                              const signed char* __restrict__ kv8,
                                              const u16* __restrict__ woT, const float* __restrict__ y1,
                                              const float* __restrict__ bnsc, const float* __restrict__ bnsh,
                                              float* __restrict__ out) {
  const int win = blockIdx.x, b = blockIdx.y, qt = blockIdx.z;
  const int T0 = win * 256;
  alignas(16) __shared__ char smem[69632];  // phase A/B: svT[128][264] u16; phase D/E: pw2 + sF
  u16* svT = reinterpret_cast<u16*>(smem);
  const int tid = threadIdx.x, wave = tid >> 6, lane = tid & 63, n = lane & 15, g = lane >> 4;
  for (int i = tid; i < 8192; i += 512) {  // 32768 i8 spikes as u32 quads
    int u = i >> 5, c4 = (i & 31) << 2;
    u32 w4 = *reinterpret_cast<const u32*>(sv8 + ((size_t)b * LP + T0 + u) * CO + c4);
#pragma unroll
    for (int j = 0; j < 4; ++j) {
      svT[(c4 + j) * 264 + u] = ((w4 >> (8 * j)) & 0xffu) ? (u16)0x3F80 : (u16)0;  // bf16 1.0 / 0.0
    }
  }
  __syncthreads();
  {
    const int qbase = wave * 32 + qt * 16;
    // q spikes (i8, 2 fragments cover K=128)
    s32x4 bq8[2];
    const signed char* qrow = sq8 + ((size_t)b * LP + T0 + qbase + n) * CO;
    bq8[0] = *reinterpret_cast<const s32x4*>(qrow + g * 16);
    bq8[1] = *reinterpret_cast<const s32x4*>(qrow + 64 + g * 16);
    // phase A: S^T[u][q] integer-exact via i8 MFMA (lane holds q=n, u = ut*16 + g*4 + r)
    s32x4 pacc[16];
#pragma unroll
    for (int ut = 0; ut < 16; ++ut) pacc[ut] = s32x4{0, 0, 0, 0};
    for (int ut = 0; ut < 16; ++ut) {
      const signed char* krow = sk8 + ((size_t)b * LP + T0 + ut * 16 + n) * CO;
      s32x4 kf0 = *reinterpret_cast<const s32x4*>(krow + g * 16);
      s32x4 kf1 = *reinterpret_cast<const s32x4*>(krow + 64 + g * 16);
      pacc[ut] = __builtin_amdgcn_mfma_i32_16x16x64_i8(kf0, bq8[0], pacc[ut], 0, 0, 0);
      pacc[ut] = __builtin_amdgcn_mfma_i32_16x16x64_i8(kf1, bq8[1], pacc[ut], 0, 0, 0);
    }
    // phase A2: window weights + pack to bf16 pairs (RNE; S integers -> identical P bits)
    const int qblk = (qbase + n) >> 6;
    u32 packed[16][2];
#pragma unroll
    for (int ut = 0; ut < 16; ++ut) {
      u16 pk[4];
#pragma unroll
      for (int r = 0; r < 4; ++r) {
        int uloc = ut * 16 + g * 4 + r;
        float wgt = (1.f / 768.f) + (((uloc >> 6) == qblk) ? (1.f / 192.f) : 0.f);
        pk[r] = f2b((float)pacc[ut][r] * wgt);
      }
      packed[ut][0] = (u32)pk[0] | ((u32)pk[1] << 16);
      packed[ut][1] = (u32)pk[2] | ((u32)pk[3] << 16);
    }
    // phase C (first): global attn, i8 exact -> acco initialized with accg/48
    f32x4 acco[8];
#pragma unroll
    for (int ct = 0; ct < 8; ++ct) {
      s32x4 ag = {0, 0, 0, 0};
      const signed char* kvrow = kv8 + ((size_t)b * CO + ct * 16 + n) * CO;
      s32x4 k0 = *reinterpret_cast<const s32x4*>(kvrow + g * 16);
      s32x4 k1 = *reinterpret_cast<const s32x4*>(kvrow + 64 + g * 16);
      ag = __builtin_amdgcn_mfma_i32_16x16x64_i8(bq8[0], k0, ag, 0, 0, 0);
      ag = __builtin_amdgcn_mfma_i32_16x16x64_i8(bq8[1], k1, ag, 0, 0, 0);
#pragma unroll
      for (int r = 0; r < 4; ++r) acco[ct][r] = (float)ag[r] * (1.f / 48.f);
    }
    // phase B: PV with P delivered by shfl: lane (n,g) needs P[q=n][u=us*32+8g+j]
    const int sl0 = n + 16 * ((g & 1) * 2);
    const int sl1 = sl0 + 16;
    const bool ghi = ((g >> 1) & 1) != 0;
#pragma unroll
    for (int us = 0; us < 8; ++us) {
      u32 a0e = (u32)__shfl((int)packed[us * 2][0], sl0, 64);
      u32 a0o = (u32)__shfl((int)packed[us * 2 + 1][0], sl0, 64);
      u32 a1e = (u32)__shfl((int)packed[us * 2][1], sl0, 64);
      u32 a1o = (u32)__shfl((int)packed[us * 2 + 1][1], sl0, 64);
      u32 a2e = (u32)__shfl((int)packed[us * 2][0], sl1, 64);
      u32 a2o = (u32)__shfl((int)packed[us * 2 + 1][0], sl1, 64);
      u32 a3e = (u32)__shfl((int)packed[us * 2][1], sl1, 64);
      u32 a3o = (u32)__shfl((int)packed[us * 2 + 1][1], sl1, 64);
      u32x4 paw = {ghi ? a0o : a0e, ghi ? a1o : a1e, ghi ? a2o : a2e, ghi ? a3o : a3e};
      bf16x8 pa = __builtin_bit_cast(bf16x8, paw);
#pragma unroll
      for (int ct = 0; ct < 8; ++ct) {
        bf16x8 bv = *reinterpret_cast<const bf16x8*>(&svT[(ct * 16 + n) * 264 + us * 32 + g * 8]);
        acco[ct] = __builtin_amdgcn_mfma_f32_16x16x32_bf16(pa, bv, acco[ct], 0, 0, 0);
      }
    }
    // phase D: attn-out tile -> per-wave bf16 scratch (svT dead after this barrier)
    __syncthreads();
    u16* pw2 = reinterpret_cast<u16*>(smem) + wave * (16 * 136);            // 34816 B total
    float* sF = reinterpret_cast<float*>(smem + 34816) + wave * (64 * 17);  // 34816 B total
#pragma unroll
    for (int ct = 0; ct < 8; ++ct) {
#pragma unroll
      for (int r = 0; r < 4; ++r) {
        pw2[(g * 4 + r) * 136 + ct * 16 + n] = f2b(acco[ct][r]);
      }
    }
    // phase E: wo GEMM; route facc through fp32 LDS tile for coalesced residual+store.
    for (int half = 0; half < 2; ++half) {
#pragma unroll
      for (int ot2 = 0; ot2 < 4; ++ot2) {
        int ot = half * 4 + ot2;
        f32x4 facc = {};
#pragma unroll
        for (int ks = 0; ks < 4; ++ks) {
          bf16x8 af = *reinterpret_cast<const bf16x8*>(&pw2[n * 136 + ks * 32 + g * 8]);
          bf16x8 bw = *reinterpret_cast<const bf16x8*>(&woT[(ot * 16 + n) * CO + ks * 32 + g * 8]);
          facc = __builtin_amdgcn_mfma_f32_16x16x32_bf16(af, bw, facc, 0, 0, 0);
        }
#pragma unroll
        for (int r = 0; r < 4; ++r) sF[(ot2 * 16 + n) * 17 + g * 4 + r] = facc[r];
      }
      // store: lane&15 = l-offset -> 16 consecutive floats per o-row (full 64B lines)
#pragma unroll
      for (int oo = 0; oo < 16; ++oo) {
        int olocal = oo * 4 + (lane >> 4);
        int o = half * 64 + olocal;
        int l = T0 + qbase + (lane & 15);
        float v = sF[olocal * 17 + (lane & 15)];
        if (l < LO) {
          size_t idx = ((size_t)b * CO + o) * LO + l;
          out[idx] = elu(y1[idx] * bnsc[o] + bnsh[o]) + v;
        }
      }
    }
  }
}

extern "C" void kernel_launch(void* const* d_in, const int* in_sizes, int n_in, void* d_out, int out_size,
                              void* d_ws, size_t ws_size, hipStream_t stream) {
  const float* x = (const float*)d_in[0];
  const float* conv_w = (const float*)d_in[1];
  const float* conv_b = (const float*)d_in[2];
  const float* gamma = (const float*)d_in[3];
  const float* beta = (const float*)d_in[4];
  const float* wq = (const float*)d_in[5];
  const float* wk = (const float*)d_in[6];
  const float* wv = (const float*)d_in[7];
  const float* wo = (const float*)d_in[8];
  (void)in_sizes; (void)n_in; (void)out_size; (void)ws_size;

  char* ws = (char*)d_ws;
  size_t off = 0;
  auto alloc = [&](size_t bytes) -> void* {
    void* p = ws + off;
    off += (bytes + 511) & ~(size_t)511;
    return p;
  };
  float* ps = (float*)alloc((size_t)B_ * CO * 4);
  float* ps2 = (float*)alloc((size_t)B_ * CO * 4);
  float* bnsc = (float*)alloc(CO * 4);
  float* bnsh = (float*)alloc(CO * 4);
  float* alphaf = (float*)alloc(CO * 4);
  float* hsum = (float*)alloc((size_t)B_ * 16 * CO * 4);
  signed char* kv8 = (signed char*)alloc((size_t)B_ * CO * CO);
  u16* wfmt = (u16*)alloc((size_t)CO * KW * CI * 2);
  u16* wThi = (u16*)alloc((size_t)4 * CO * CO * 2);
  u16* wTlo = (u16*)alloc((size_t)4 * CO * CO * 2);
  u16* wT3 = (u16*)alloc((size_t)3 * 4 * 8 * 1024 * 2);
  float* y1 = (float*)alloc((size_t)B_ * CO * LO * 4);
  signed char* sqb8 = (signed char*)alloc((size_t)B_ * LP * CO);
  signed char* skb8 = (signed char*)alloc((size_t)B_ * LP * CO);
  signed char* svb8 = (signed char*)alloc((size_t)B_ * LP * CO);

  hipLaunchKernelGGL(k_prep, dim3(132), dim3(256), 0, stream, conv_w, wq, wk, wv, wo, wfmt, alphaf, wThi,
                     wTlo, wT3);
  hipLaunchKernelGGL(k_conv, dim3(80, B_), dim3(256), 0, stream, x, wfmt, conv_b, alphaf, y1);
  hipLaunchKernelGGL(k_stats, dim3(CO, B_), dim3(256), 0, stream, y1, ps, ps2);
  hipLaunchKernelGGL(k_bnparams, dim3(1), dim3(CO), 0, stream, ps, ps2, gamma, beta, bnsc, bnsh);
  hipLaunchKernelGGL(k_qkv, dim3(20, B_), dim3(256), 0, stream, y1, bnsc, bnsh, wT3, sqb8, skb8, svb8);
  hipLaunchKernelGGL(k_poolh, dim3(CO, B_), dim3(64), 0, stream, y1, bnsc, bnsh, hsum);
  hipLaunchKernelGGL(k_kv2, dim3(B_), dim3(256), 0, stream, hsum, wk, wv, kv8);
  hipLaunchKernelGGL(k_attn, dim3(10, B_, 2), dim3(512), 0, stream, sqb8, skb8, svb8, kv8, wThi + 3 * CO * CO,
                     y1, bnsc, bnsh, (float*)d_out);
}